// Round 7
// baseline (239.850 us; speedup 1.0000x reference)
//
#include <hip/hip_runtime.h>

typedef unsigned short ushort_t;
typedef unsigned int uint_t;
typedef __attribute__((ext_vector_type(8))) short bf16x8;
typedef __attribute__((ext_vector_type(4))) float f32x4;
typedef __attribute__((ext_vector_type(2))) float f32x2;

#define C_DIM 64
#define P_DIM 1296
#define N_DIM 2000
#define B_DIM 256
#define K_DIM (C_DIM * P_DIM)               // 82944
#define XB_ELEMS (B_DIM * K_DIM)            // 21233664
#define XB_ELEMS_PAD (XB_ELEMS + 256)       // 21233920
#define XB_BYTES ((size_t)XB_ELEMS_PAD * 2) // 42467840
#define SLICES 32
#define OUT_ELEMS (B_DIM * N_DIM)           // 512000
#define NSTEP 82                            // 2 channels x 41 BK=32 steps

static __device__ __forceinline__ ushort_t f2bf(float f) {
  unsigned u = __builtin_bit_cast(unsigned, f);
  u += 0x7fffu + ((u >> 16) & 1u);
  return (ushort_t)(u >> 16);
}

// ---------------- x (fp32) -> Xb (bf16) with zeroed pad tail ----------------
__global__ void klindt_cvt_kernel(const f32x4* __restrict__ x,
                                  unsigned long long* __restrict__ xb) {
  int idx = blockIdx.x * 256 + threadIdx.x;
  if (idx >= XB_ELEMS_PAD / 4) return;
  unsigned long long r = 0ull;
  if (idx < XB_ELEMS / 4) {
    f32x4 v = __builtin_nontemporal_load(&x[idx]);  // stream-once
    r = (unsigned long long)f2bf(v[0]) | ((unsigned long long)f2bf(v[1]) << 16) |
        ((unsigned long long)f2bf(v[2]) << 32) |
        ((unsigned long long)f2bf(v[3]) << 48);
  }
  xb[idx] = r;  // cached: re-read 16x by GEMM
}

// ---------------- main GEMM: partials[slice][b][n] ----------------
// BM=256 (full M, mw read exactly once), BN=128, BK=32. 512 threads = 8 waves
// (4Mx2N), wave tile 64x64 = acc[4][4] of 16x16x32 bf16 MFMAs.
// H10: B staging is (2n x 4p)/thread with float2 NON-TEMPORAL loads -> each
// wave instruction covers ONE full 512B (p,c)-segment (sequential DRAM
// bursts), and mw no longer evicts the XCD-pinned xb from L2.
// XCD pin (H9): slice = (bid&7) + 8*((bid>>3)&3), 16 n-tiles per slice share
// one XCD's L2 for the A (xb) re-reads.
__global__ void __launch_bounds__(512, 4) klindt_gemm_kernel(
    const char* __restrict__ xbb, const char* __restrict__ mwb,
    const float* __restrict__ rw, float* __restrict__ partials) {
  __shared__ ushort_t sA[2][8192];  // [256 m][32 k] bf16, 64B rows, XOR-swz
  __shared__ ushort_t sB[2][4096];  // [128 n][32 k] bf16, 64B rows, XOR-swz

  const int tid = threadIdx.x;
  const int lane = tid & 63;
  const int wid = tid >> 6;
  const int wm = wid >> 1;
  const int wn = wid & 1;
  const int bid = blockIdx.x;
  const int slice = (bid & 7) + 8 * ((bid >> 3) & 3);  // 0..31, XCD-pinned
  const int n0 = (bid >> 5) * 128;                     // 16 n-tiles
  const int c0 = slice * 2;

  f32x4 acc[4][4];
#pragma unroll
  for (int i = 0; i < 4; ++i)
#pragma unroll
    for (int j = 0; j < 4; ++j) {
      acc[i][j][0] = 0.f; acc[i][j][1] = 0.f;
      acc[i][j][2] = 0.f; acc[i][j][3] = 0.f;
    }

  // ---- A staging: linear LDS dest, inverse-swizzled global src (rule #21) --
  uint_t a_gbase[2]; int a_doff[2];
#pragma unroll
  for (int it = 0; it < 2; ++it) {
    int chunk = it * 512 + tid;
    int row = chunk >> 2, t4 = chunk & 3;
    int ss = t4 ^ ((row >> 1) & 3);
    a_gbase[it] = (uint_t)(row * K_DIM + ss * 8) * 2u;  // byte off into xb
    a_doff[it] = chunk * 8;                             // elem off into sA
  }
  // ---- B staging: thread = (n-pair np, p-quad kq). Wave (kq==wid) loads
  //      4 x 512B fully-contiguous segments per step. ----
  const int np = tid & 63;   // n-pair 0..63 -> rows 2np, 2np+1
  const int kq = tid >> 6;   // p-quad 0..7  -> p = 4kq + j
  const uint_t G = (uint_t)(n0 >> 1) + (uint_t)np;  // global n-pair idx
  const bool okn = G < 1000u;
  const uint_t Gc = okn ? G : 999u;                 // clamp addr
  const uint_t b_goff = (uint_t)kq * 2048000u + Gc * 8u;  // byte off into mw
  // sB slot-XOR identical to read side: slot(n,ks) = ks ^ ((n>>1)&3)
  const int b_eoff = (2 * np) * 32 + (((kq >> 1) ^ (np & 3)) * 8) + (kq & 1) * 4;
  f32x2 rvl2, rvh2;
  {
    f32x2 rl = *(const f32x2*)(rw + (size_t)c0 * N_DIM + 2 * Gc);
    f32x2 rh = *(const f32x2*)(rw + (size_t)(c0 + 1) * N_DIM + 2 * Gc);
    f32x2 z; z[0] = 0.f; z[1] = 0.f;
    rvl2 = okn ? rl : z;
    rvh2 = okn ? rh : z;
  }

  // ---- fragment read offsets (swizzle-consistent) ----
  const int r15 = lane & 15, g4 = lane >> 4;
  const int swz = g4 ^ ((r15 >> 1) & 3);
  const int aoffbase = (wm * 64 + r15) * 32 + swz * 8;
  const int boffbase = (wn * 64 + r15) * 32 + swz * 8;

  f32x2 mvE[4], mvO[4];  // B register double-buffer (static parity)

  auto issueA = [&](int buf, int t) {
    int half = (t >= 41) ? 1 : 0;
    int sp = t - 41 * half;
    uint_t kb = ((uint_t)(c0 + half) * (uint_t)P_DIM + (uint_t)sp * 32u) * 2u;
#pragma unroll
    for (int it = 0; it < 2; ++it) {
      const char* g = xbb + (a_gbase[it] + kb);
      __builtin_amdgcn_global_load_lds(
          (const __attribute__((address_space(1))) unsigned int*)g,
          (__attribute__((address_space(3))) unsigned int*)(&sA[buf][a_doff[it]]),
          16, 0, 0);
    }
  };
  auto computeStep = [&](int buf) {
    bf16x8 bfr[4];
#pragma unroll
    for (int fn = 0; fn < 4; ++fn)
      bfr[fn] = *(const bf16x8*)(&sB[buf][boffbase + fn * 512]);
    __builtin_amdgcn_s_setprio(1);
#pragma unroll
    for (int fm = 0; fm < 4; ++fm) {
      bf16x8 afr = *(const bf16x8*)(&sA[buf][aoffbase + fm * 512]);
#pragma unroll
      for (int fn = 0; fn < 4; ++fn)
        acc[fm][fn] = __builtin_amdgcn_mfma_f32_16x16x32_bf16(
            afr, bfr[fn], acc[fm][fn], 0, 0, 0);
    }
    __builtin_amdgcn_s_setprio(0);
  };

#define ISSUE_B(MV, T)                                                        \
  do {                                                                        \
    int half_ = ((T) >= 41) ? 1 : 0;                                          \
    int sp_ = (T)-41 * half_;                                                 \
    uint_t ub_ = (uint_t)sp_ * 16384000u + (uint_t)(c0 + half_) * 8000u;      \
    const char* bp_ = mwb + (ub_ + b_goff);                                   \
    if ((sp_ < 40) || (kq < 4)) { /* wave-uniform k-tail guard */             \
      _Pragma("unroll") for (int j_ = 0; j_ < 4; ++j_)                        \
        MV[j_] = __builtin_nontemporal_load(                                  \
            (const f32x2*)(bp_ + (uint_t)j_ * 512000u));                      \
    } else {                                                                  \
      _Pragma("unroll") for (int j_ = 0; j_ < 4; ++j_) {                      \
        MV[j_][0] = 0.f; MV[j_][1] = 0.f;                                     \
      }                                                                       \
    }                                                                         \
  } while (0)

#define WRITE_B(BUF, MV, T)                                                   \
  do {                                                                        \
    f32x2 rv_ = ((T) >= 41) ? rvh2 : rvl2;                                    \
    unsigned long long pk0_ = 0ull, pk1_ = 0ull;                              \
    _Pragma("unroll") for (int j_ = 0; j_ < 4; ++j_) {                        \
      pk0_ |= (unsigned long long)f2bf(MV[j_][0] * rv_[0]) << (16 * j_);      \
      pk1_ |= (unsigned long long)f2bf(MV[j_][1] * rv_[1]) << (16 * j_);      \
    }                                                                         \
    *(unsigned long long*)(&sB[BUF][b_eoff]) = pk0_;                          \
    *(unsigned long long*)(&sB[BUF][b_eoff + 32]) = pk1_;                     \
  } while (0)

  // ---- prologue ----
  ISSUE_B(mvE, 0);
  issueA(0, 0);
  WRITE_B(0, mvE, 0);  // implicit wait drains B(0); A(0) stays in flight
  ISSUE_B(mvO, 1);
  asm volatile("s_waitcnt vmcnt(4) lgkmcnt(0)" ::: "memory");
  __builtin_amdgcn_sched_barrier(0);
  __builtin_amdgcn_s_barrier();
  __builtin_amdgcn_sched_barrier(0);

#define BODY(S, MV_ISSUE, MV_WRITE)                                           \
  {                                                                           \
    issueA(((S) + 1) & 1, (S) + 1);                                           \
    ISSUE_B(MV_ISSUE, (S) + 2);                                               \
    computeStep((S)&1);                                                       \
    WRITE_B(((S) + 1) & 1, MV_WRITE, (S) + 1);                                \
    asm volatile("s_waitcnt vmcnt(4) lgkmcnt(0)" ::: "memory");               \
    __builtin_amdgcn_sched_barrier(0);                                        \
    __builtin_amdgcn_s_barrier();                                             \
    __builtin_amdgcn_sched_barrier(0);                                        \
  }

  // ---- main loop: steps 0..79 ----
  for (int s = 0; s < 80; s += 2) {
    BODY(s, mvE, mvO);
    BODY(s + 1, mvO, mvE);
  }
  // ---- peel s=80 (no B prefetch; full drain so A(81) is guaranteed) ----
  issueA(1, 81);
  computeStep(0);
  WRITE_B(1, mvO, 81);
  asm volatile("s_waitcnt vmcnt(0) lgkmcnt(0)" ::: "memory");
  __builtin_amdgcn_sched_barrier(0);
  __builtin_amdgcn_s_barrier();
  __builtin_amdgcn_sched_barrier(0);
  // ---- s=81 ----
  computeStep(1);

  // ---- epilogue: fp32 partials (non-temporal: never re-read by this kernel)
  float* pb = partials + (size_t)slice * OUT_ELEMS;
#pragma unroll
  for (int fm = 0; fm < 4; ++fm) {
#pragma unroll
    for (int fn = 0; fn < 4; ++fn) {
      int nn = n0 + wn * 64 + fn * 16 + r15;
      if (nn < N_DIM) {
#pragma unroll
        for (int rr = 0; rr < 4; ++rr) {
          int m = wm * 64 + fm * 16 + g4 * 4 + rr;
          __builtin_nontemporal_store(acc[fm][fn][rr], &pb[m * N_DIM + nn]);
        }
      }
    }
  }
#undef BODY
#undef ISSUE_B
#undef WRITE_B
}

// ---------------- deterministic split-K reduction ----------------
__global__ void klindt_reduce_kernel(const float* __restrict__ part,
                                     float* __restrict__ out) {
  int i = blockIdx.x * 256 + threadIdx.x;
  if (i < OUT_ELEMS) {
    float s = 0.f;
#pragma unroll
    for (int k = 0; k < SLICES; ++k)
      s += __builtin_nontemporal_load(&part[(size_t)k * OUT_ELEMS + i]);
    out[i] = s;
  }
}

extern "C" void kernel_launch(void* const* d_in, const int* in_sizes, int n_in,
                              void* d_out, int out_size, void* d_ws,
                              size_t ws_size, hipStream_t stream) {
  (void)in_sizes; (void)n_in; (void)out_size; (void)ws_size;
  const float* x = (const float*)d_in[0];
  const char* mwb = (const char*)d_in[1];
  const float* rw = (const float*)d_in[2];
  float* out = (float*)d_out;

  char* xbb = (char*)d_ws;
  float* partials = (float*)((char*)d_ws + XB_BYTES);

  {
    int nvec = XB_ELEMS_PAD / 4;
    int grid = (nvec + 255) / 256;
    klindt_cvt_kernel<<<grid, 256, 0, stream>>>((const f32x4*)x,
                                                (unsigned long long*)xbb);
  }
  {
    klindt_gemm_kernel<<<512, 512, 0, stream>>>(xbb, mwb, rw, partials);
  }
  {
    int grid = (OUT_ELEMS + 255) / 256;
    klindt_reduce_kernel<<<grid, 256, 0, stream>>>(partials, out);
  }
}